// Round 23
// baseline (379.723 us; speedup 1.0000x reference)
//
#include <hip/hip_runtime.h>
#include <hip/hip_bf16.h>

using bf16 = __hip_bfloat16;
typedef __attribute__((ext_vector_type(8))) short short8;   // 8 x bf16 (4 VGPRs)
typedef __attribute__((ext_vector_type(4))) float f32x4;
typedef __attribute__((ext_vector_type(4))) short short4v;

#define B_   16
#define C_   512
#define N_   4096
#define NG   8
#define GRP_ELEMS (64 * 4096)
static constexpr float kScale = 0.04419417382415922f;  // 512^-0.5
#define SPART_STRIDE 4194304ULL  // 16*512*512 f32 elements per Gram partial

// ---------------- memory layout ----------------
// d_ws: WQ 1.5MB | WP 0.5MB | PART/SUM/CHS/u/w | WVT | BIAS2 | Qslot | Kslot | XNT
//  Qslot: xn_cn (b,c,n) bf16 64MB -> dead after Gram -> G2 (hi|lo) 16MB @+0,
//         P bf16 16MB @+16MB, att_t 8MB @+32MB.
//  Kslot: Gram partials f32 4x16MB (dead after greduce) -> W2 8MB @+0, W3 @+8MB.
// d_out: S f32 16MB scratch; final GEMM rewrites all of d_out.
#define OFF_WQ    0ULL
#define OFF_WP    0x180000ULL
#define OFF_PART  0x204000ULL
#define OFF_SUM   0x210000ULL
#define OFF_CHS   0x218000ULL
#define OFF_U     0x220000ULL
#define OFF_W     0x230000ULL
#define OFF_WVT   0x240000ULL
#define OFF_BV2   0x2C0000ULL
#define OFF_Q     0x400000ULL
#define OFF_K     (OFF_Q  + 0x4000000ULL)
#define OFF_VT    (OFF_K  + 0x4000000ULL)   // hosts xnt (b,n,c)
#define OFF_XNC   OFF_Q
#define OFF_G2    OFF_Q
#define OFF_P     (OFF_Q + 0x1000000ULL)
#define OFF_ATT   (OFF_Q + 0x2000000ULL)
#define OFF_GP    OFF_K
#define OFF_W2    OFF_K
#define OFF_W3    (OFF_K + 0x800000ULL)

typedef __attribute__((address_space(1))) const void* as1cvp;
typedef __attribute__((address_space(3))) void* as3vp;

__device__ inline void gload_lds16(const void* g, void* l) {
  __builtin_amdgcn_global_load_lds((as1cvp)g, (as3vp)l, 16, 0, 0);
}

__device__ inline short bf16bits(float v) {
  bf16 h = __float2bfloat16(v);
  return *reinterpret_cast<short*>(&h);
}

#define BARX() __builtin_amdgcn_s_barrier()
#define SFEN() __builtin_amdgcn_sched_barrier(0)
#define LG0()  asm volatile("s_waitcnt lgkmcnt(0)" ::: "memory")
#define VM4()  asm volatile("s_waitcnt vmcnt(4)" ::: "memory")
#define VM0()  asm volatile("s_waitcnt vmcnt(0)" ::: "memory")

// -------- K0: prep = weight cvt (blocks 0..3071) + GN stats + chan sums ----
__global__ __launch_bounds__(256) void prep(const float* __restrict__ wq,
                                            const float* __restrict__ wp,
                                            const float* __restrict__ x,
                                            bf16* __restrict__ oq,
                                            bf16* __restrict__ op,
                                            bf16* __restrict__ wvt,
                                            float* __restrict__ part,
                                            float* __restrict__ chansum) {
  if (blockIdx.x < 3072) {
    int i = blockIdx.x * 256 + threadIdx.x;
    oq[i] = __float2bfloat16(wq[i]);
    if (i < 512 * 512) {
      op[i] = __float2bfloat16(wp[i]);
      const int d = i >> 9, c = i & 511;   // Wv row d, col c
      wvt[c * 512 + d] = __float2bfloat16(wq[(1024 + d) * 512 + c]);
    }
    return;
  }
  const int bid = blockIdx.x - 3072;       // 0..2047
  const int bg  = bid >> 4;                // group (b*8+g)
  const int seg = bid & 15;                // 4-channel segment
  const float4* p = (const float4*)(x + (size_t)bg * GRP_ELEMS + seg * 16384);
  float a[4] = {0.f, 0.f, 0.f, 0.f};       // per-channel sums
  float q = 0.f;
#pragma unroll
  for (int i = 0; i < 16; ++i) {           // channel j = i>>2 (t<256 exact)
    float4 v = p[threadIdx.x + i * 256];
    a[i >> 2] += v.x + v.y + v.z + v.w;
    q += v.x * v.x + v.y * v.y + v.z * v.z + v.w * v.w;
  }
  for (int off = 32; off; off >>= 1) {
#pragma unroll
    for (int j = 0; j < 4; ++j) a[j] += __shfl_xor(a[j], off);
    q += __shfl_xor(q, off);
  }
  __shared__ float red[4][5];
  int w = threadIdx.x >> 6;
  if ((threadIdx.x & 63) == 0) {
#pragma unroll
    for (int j = 0; j < 4; ++j) red[w][j] = a[j];
    red[w][4] = q;
  }
  __syncthreads();
  if (threadIdx.x == 0) {
    float c0 = red[0][0] + red[1][0] + red[2][0] + red[3][0];
    float c1 = red[0][1] + red[1][1] + red[2][1] + red[3][1];
    float c2 = red[0][2] + red[1][2] + red[2][2] + red[3][2];
    float c3 = red[0][3] + red[1][3] + red[2][3] + red[3][3];
    float Q  = red[0][4] + red[1][4] + red[2][4] + red[3][4];
    part[bid * 2]     = c0 + c1 + c2 + c3;
    part[bid * 2 + 1] = Q;
    const int b = bg >> 3, c = (bg & 7) * 64 + seg * 4;
    float* cs = chansum + b * 512 + c;
    cs[0] = c0; cs[1] = c1; cs[2] = c2; cs[3] = c3;
  }
}

// ------- K2: stats-from-partials + normalize+affine -> xnt & xncn ----------
__global__ __launch_bounds__(256) void gn_apply_t(const float* __restrict__ x,
                                                  const float* __restrict__ part,
                                                  const float* __restrict__ nw,
                                                  const float* __restrict__ nb,
                                                  bf16* __restrict__ xnt,
                                                  bf16* __restrict__ xncn) {
  const int nt = blockIdx.x;
  const int ct = blockIdx.y;
  const int b  = blockIdx.z;
  __shared__ float tile[64][65];
  const int bg = b * NG + ct;
  float Sm = 0.f, Qm = 0.f;
#pragma unroll
  for (int i = 0; i < 16; ++i) {
    Sm += part[(bg * 16 + i) * 2];
    Qm += part[(bg * 16 + i) * 2 + 1];
  }
  const float mean = Sm * (1.f / GRP_ELEMS);
  const float var  = Qm * (1.f / GRP_ELEMS) - mean * mean;
  const float rstd = rsqrtf(var + 1e-5f);

  const int r16 = threadIdx.x >> 4;        // 0..15
  const int q4  = (threadIdx.x & 15) * 4;  // 0..60
#pragma unroll
  for (int p = 0; p < 4; ++p) {
    const int cl = p * 16 + r16;
    const int c  = ct * 64 + cl;
    const float g  = nw[c] * rstd;
    const float sh = nb[c] - mean * g;
    float4 v = *(const float4*)(x + ((size_t)b * C_ + c) * N_ + nt * 64 + q4);
    const float x0 = v.x * g + sh, x1 = v.y * g + sh;
    const float x2 = v.z * g + sh, x3 = v.w * g + sh;
    tile[cl][q4] = x0; tile[cl][q4 + 1] = x1;
    tile[cl][q4 + 2] = x2; tile[cl][q4 + 3] = x3;
    short4v s4 = {bf16bits(x0), bf16bits(x1), bf16bits(x2), bf16bits(x3)};
    *(short4v*)(xncn + ((size_t)b * C_ + c) * N_ + nt * 64 + q4) = s4;
  }
  __syncthreads();
#pragma unroll
  for (int p = 0; p < 4; ++p) {
    const int nl = p * 16 + r16;
    short4v s4 = {bf16bits(tile[q4][nl]), bf16bits(tile[q4 + 1][nl]),
                  bf16bits(tile[q4 + 2][nl]), bf16bits(tile[q4 + 3][nl])};
    *(short4v*)(xnt + ((size_t)b * N_ + nt * 64 + nl) * C_ + ct * 64 + q4) = s4;
  }
}

// ---- K3: ssum[b,c] = sum_n xn = g*rowsum_x + 4096*sh (exact, from chansum) -
__global__ __launch_bounds__(512) void mk_ssum(const float* __restrict__ chansum,
                                               const float* __restrict__ part,
                                               const float* __restrict__ nw,
                                               const float* __restrict__ nb,
                                               float* __restrict__ ssum) {
  const int b = blockIdx.x, c = threadIdx.x;
  const int bg = b * NG + (c >> 6);
  float Sm = 0.f, Qm = 0.f;
#pragma unroll
  for (int i = 0; i < 16; ++i) {
    Sm += part[(bg * 16 + i) * 2];
    Qm += part[(bg * 16 + i) * 2 + 1];
  }
  const float mean = Sm * (1.f / GRP_ELEMS);
  const float var  = Qm * (1.f / GRP_ELEMS) - mean * mean;
  const float rstd = rsqrtf(var + 1e-5f);
  const float g  = nw[c] * rstd;
  const float sh = nb[c] - mean * g;
  ssum[b * 512 + c] = g * chansum[b * 512 + c] + 4096.f * sh;
}

// ---- K4: reduce Gram partials -> G2 (b,e,[hi|lo]); mirror lower-left ------
__global__ __launch_bounds__(256) void greduce(const float* __restrict__ gp,
                                               bf16* __restrict__ g2) {
  const int b  = blockIdx.x >> 6;
  const int t  = blockIdx.x & 63;
  const int te = t >> 3, tk = t & 7;
  const bool mir = (te >= 4 && tk < 4);    // lower-left quadrant: mirror
  const size_t gbase = (size_t)b * 262144;
  const int r  = threadIdx.x >> 2;         // 0..63
  const int c0 = (threadIdx.x & 3) * 16;   // 0,16,32,48
  __shared__ float T[64][65];
  const int sre = mir ? tk : te, srk = mir ? te : tk;
  const float* src = gp + gbase + (size_t)(sre * 64 + r) * 512 + srk * 64 + c0;
#pragma unroll
  for (int j = 0; j < 16; j += 4) {
    float4 v0 = *(const float4*)(src + j);
    float4 v1 = *(const float4*)(src + SPART_STRIDE + j);
    float4 v2 = *(const float4*)(src + 2 * SPART_STRIDE + j);
    float4 v3 = *(const float4*)(src + 3 * SPART_STRIDE + j);
    T[r][c0 + j]     = v0.x + v1.x + v2.x + v3.x;
    T[r][c0 + j + 1] = v0.y + v1.y + v2.y + v3.y;
    T[r][c0 + j + 2] = v0.z + v1.z + v2.z + v3.z;
    T[r][c0 + j + 3] = v0.w + v1.w + v2.w + v3.w;
  }
  __syncthreads();
  const int e = te * 64 + r;
  bf16* hi = g2 + ((size_t)b * 512 + e) * 1024 + tk * 64 + c0;
#pragma unroll
  for (int j = 0; j < 16; ++j) {
    const float g = mir ? T[c0 + j][r] : T[r][c0 + j];
    bf16 h = __float2bfloat16(g);
    hi[j]       = h;
    hi[512 + j] = __float2bfloat16(g - __bfloat162float(h));
  }
}

// ---------------- K5: u = Wq s, w = Wk s (fp32, exact) ----------------
__global__ __launch_bounds__(512) void gemv_uw(const float* __restrict__ qw,
                                               const float* __restrict__ s,
                                               float* __restrict__ u,
                                               float* __restrict__ w) {
  const int b = blockIdx.x >> 1, which = blockIdx.x & 1;
  const int c = threadIdx.x;
  const float* row = qw + (size_t)(which * 512 + c) * 512;
  const float* sv = s + b * 512;
  float acc = 0.f;
  for (int d = 0; d < 512; d += 4) {
    float4 wv = *(const float4*)(row + d);
    float4 s4 = *(const float4*)(sv + d);
    acc += wv.x * s4.x + wv.y * s4.y + wv.z * s4.z + wv.w * s4.w;
  }
  (which ? w : u)[b * 512 + c] = acc;
}

// ------- K7: bias2[b][o] = proj_b[o] + sum_d W2[b][o][d] * bv[d] -----------
__global__ __launch_bounds__(512) void gemv_bv2(const bf16* __restrict__ w2,
                                                const float* __restrict__ qkv_b,
                                                const float* __restrict__ proj_b,
                                                float* __restrict__ bias2) {
  const int b = blockIdx.x, o = threadIdx.x;
  const bf16* row = w2 + (size_t)b * 262144 + o * 512;
  float acc = proj_b[o];
  for (int d = 0; d < 512; d += 8) {
    short8 v8 = *(const short8*)(row + d);
#pragma unroll
    for (int i = 0; i < 8; ++i) {
      short t = v8[i];
      acc += __bfloat162float(*reinterpret_cast<const bf16*>(&t)) *
             qkv_b[1024 + d + i];
    }
  }
  bias2[b * 512 + o] = acc;
}

// =================================================================
// gemm128: 128x128-tile NT bf16 GEMM, BK=32 (round-4 verified core).
// MODE 2: C[b] = A(/b)*B(/b)^T bf16; 256 blk (P / W2 / W3)
// MODE 4: same, A k-index wraps mod 512 (A=Wq, B=[Ghi|Glo], K=1024); 256 blk
// MODE 5: S[b] = (A*B^T + rank-1 corr) * kScale, f32; 256 blk
// MODE 3: final, 2048 blk (M-fastest for B-panel sharing):
//         out = A(W3/b)*B(xnt/b)^T + bias2[b][row] + resid
// =================================================================
template<int MODE>
__global__ __launch_bounds__(256) void gemm128(
    const bf16* __restrict__ Ag, const bf16* __restrict__ Bg,
    int K, int lda, int ldb, long long sA, long long sB,
    const float* __restrict__ bias,
    void* __restrict__ o0, void* __restrict__ o1, void* __restrict__ o2,
    const float* __restrict__ resid) {
  __shared__ __align__(16) bf16 As[128 * 32];
  __shared__ __align__(16) bf16 Bs[128 * 32];
  int bx, by, bz;
  if constexpr (MODE == 3) {
    const int s = ((blockIdx.x & 7) * 256) + (blockIdx.x >> 3);  // 2048 blocks
    by = s & 3; bx = (s >> 2) & 31; bz = s >> 7;
  } else {
    const int s = ((blockIdx.x & 7) * 32) + (blockIdx.x >> 3);   // 256 blocks
    bx = s & 3; by = (s >> 2) & 3; bz = s >> 4;
  }
  const bf16* A = Ag + (size_t)bz * sA + (size_t)by * 128 * lda;
  const bf16* B = Bg + (size_t)bz * sB + (size_t)bx * 128 * ldb;
  const int tid  = threadIdx.x;
  const int lane = tid & 63;
  const int wv   = tid >> 6;
  const int wr = wv >> 1, wc = wv & 1;
  const int r0 = wr * 64, c0 = wc * 64;
  const int mrow = lane & 15, krow = lane >> 4;
  const int i0 = tid, i1 = tid + 256;

  f32x4 acc[4][4];
#pragma unroll
  for (int mi = 0; mi < 4; ++mi)
#pragma unroll
    for (int ni = 0; ni < 4; ++ni)
#pragma unroll
      for (int r = 0; r < 4; ++r) acc[mi][ni][r] = 0.f;

  for (int k0 = 0; k0 < K; k0 += 32) {
    const int ka = (MODE == 4) ? (k0 & 511) : k0;
    gload_lds16(A + (size_t)(i0 >> 2) * lda + ka + (i0 & 3) * 8, (char*)As + i0 * 16);
    gload_lds16(A + (size_t)(i1 >> 2) * lda + ka + (i1 & 3) * 8, (char*)As + i1 * 16);
    gload_lds16(B + (size_t)(i0 >> 2) * ldb + k0 + (i0 & 3) * 8, (char*)Bs + i0 * 16);
    gload_lds16(B + (size_t)(i1 >> 2) * ldb + k0 + (i1 & 3) * 8, (char*)Bs + i1 * 16);
    __syncthreads();
    short8 af[4], bf_[4];
#pragma unroll
    for (int mi = 0; mi < 4; ++mi)
      af[mi] = *(const short8*)((const char*)As + (r0 + mi * 16 + mrow) * 64 + krow * 16);
#pragma unroll
    for (int ni = 0; ni < 4; ++ni)
      bf_[ni] = *(const short8*)((const char*)Bs + (c0 + ni * 16 + mrow) * 64 + krow * 16);
#pragma unroll
    for (int mi = 0; mi < 4; ++mi)
#pragma unroll
      for (int ni = 0; ni < 4; ++ni)
        acc[mi][ni] = __builtin_amdgcn_mfma_f32_16x16x32_bf16(af[mi], bf_[ni],
                                                              acc[mi][ni], 0, 0, 0);
    __syncthreads();
  }

#pragma unroll
  for (int mi = 0; mi < 4; ++mi)
#pragma unroll
    for (int ni = 0; ni < 4; ++ni) {
      const int col = bx * 128 + c0 + ni * 16 + mrow;
#pragma unroll
      for (int r = 0; r < 4; ++r) {
        const int row = by * 128 + r0 + mi * 16 + krow * 4 + r;
        const float v = acc[mi][ni][r];
        if constexpr (MODE == 5) {
          const float* uu = (const float*)o1;
          const float* ww = (const float*)o2;
          const float bq = bias[row], bk = bias[512 + col];
          const float corr = uu[bz * 512 + row] * bk + bq * ww[bz * 512 + col] +
                             4096.f * bq * bk;
          ((float*)o0)[(size_t)bz * 262144 + row * 512 + col] = (v + corr) * kScale;
        } else if constexpr (MODE == 3) {
          const size_t addr = ((size_t)bz * C_ + row) * N_ + col;
          ((float*)o0)[addr] = v + bias[(bz << 9) + row] + resid[addr];
        } else {
          ((bf16*)o0)[(size_t)bz * 262144 + row * 512 + col] = __float2bfloat16(v);
        }
      }
    }
}

// =================================================================
// 8-phase 256x256 NT bf16 GEMM (round-8/10 verified schedule, UNCHANGED).
// MODE 1: Gram 192 blk, K=1024 split-4 over n: tiles {(0,0),(1,1),(0,1)}
// =================================================================
template<int MODE>
__global__ __launch_bounds__(512, 2) void gemm8p(
    const bf16* __restrict__ Ag, const bf16* __restrict__ Bg,
    int lda, int ldb, long long sA, long long sB,
    const float* __restrict__ bias,
    void* __restrict__ o0, void* __restrict__ o1, void* __restrict__ o2,
    const float* __restrict__ resid) {
  __shared__ __align__(16) bf16 smem[8][8192];  // [A:0-3 | B:4-7][buf*2+half]

  constexpr int NIT = 8;
  const int id = blockIdx.x;
  const int s = (id & 7) * 24 + (id >> 3);      // 192 blocks
  const int tile = s % 3, rest = s / 3;         // 0=(0,0) 1=(1,1) 2=(0,1)
  const int part = rest & 3, bz = rest >> 2;
  const int by = (tile == 1) ? 1 : 0;
  const int bx = (tile == 0) ? 0 : 1;

  const bf16* Apan = Ag + (size_t)bz * sA + (size_t)by * 256 * lda + (size_t)part * 1024;
  const bf16* Bpan = Bg + (size_t)bz * sB + (size_t)bx * 256 * ldb + (size_t)part * 1024;

  const int tid  = threadIdx.x;
  const int lane = tid & 63;
  const int wid  = tid >> 6;
  const int wr   = wid >> 2;
  const int wc   = wid & 3;
  const int mrow = lane & 15, krow = lane >> 4;
  const int wrr  = wr * 64, wcc = wc * 32;

  auto stage = [&](int mat, int buf, int half, int kt) {
    const bf16* gb = mat ? Bpan : Apan;
    const int ld = mat ? ldb : lda;
    char* reg = (char*)smem[mat * 4 + buf * 2 + half];
#pragma unroll
    for (int j = 0; j < 2; ++j) {
      const int idx = j * 512 + tid;
      const int r   = idx >> 3;
      const int c8  = (tid & 7) ^ (r & 7);
      gload_lds16(gb + (size_t)(half * 128 + r) * ld + kt * 64 + c8 * 8,
                  reg + idx * 16);
    }
  };

  short8 a[4][2], b0[2][2], b1[2][2];
  auto ldA = [&](int buf, int qm) {
    const char* reg = (const char*)smem[buf * 2 + qm];
#pragma unroll
    for (int mi = 0; mi < 4; ++mi) {
      const int lr = wrr + mi * 16 + mrow;
#pragma unroll
      for (int s2 = 0; s2 < 2; ++s2)
        a[mi][s2] = *(const short8*)(reg + lr * 128 +
                                     (((s2 * 4 + krow) ^ (lr & 7)) << 4));
    }
  };
  auto ldB = [&](short8 (&b)[2][2], int buf, int qn) {
    const char* reg = (const char*)smem[4 + buf * 2 + qn];
#pragma unroll
    for (int ni = 0; ni < 2; ++ni) {
      const int lr = wcc + ni * 16 + mrow;
#pragma unroll
      for (int s2 = 0; s2 < 2; ++s2)
        b[ni][s2] = *(const short8*)(reg + lr * 128 +
                                     (((s2 * 4 + krow) ^ (lr & 7)) << 4));
    }
  };

  f32x4 acc[2][2][4][2];
#pragma unroll
  for (int p = 0; p < 2; ++p)
#pragma unroll
    for (int q = 0; q < 2; ++q)
#pragma unroll
      for (int m = 0; m < 4; ++m)
#pragma unroll
        for (int n = 0; n < 2; ++n)
#pragma unroll
          for (int r = 0; r < 4; ++r) acc[p][q][m][n][r] = 0.f;

  auto mm = [&](short8 (&b)[2][2], f32x4 (&c)[4][2]) {
    __builtin_amdgcn_s_setprio(1);
#pragma unroll
    for (int mi = 0; mi < 4; ++mi)
#pragma unroll
      for (int ni = 0; ni < 2; ++ni)
#pragma unroll
        for (int s2 = 0; s2 < 2; ++s2)
          c[mi][ni] = __builtin_amdgcn_mfma_f32_16x16x32_bf16(
              a[mi][s2], b[ni][s2], c[mi][ni], 0, 0, 0);
    __builtin_amdgcn_s_setprio(0);
  };

  // ---- prologue: K-tile0 all 4 halves, K-tile1 Aa+Ba ----
  stage(0, 0, 0, 0); stage(0, 0, 1, 0); stage(1, 0, 0, 0); stage(1, 0, 1, 0);
  stage(0, 1, 0, 1); stage(1, 1, 0, 1);
  VM4(); BARX(); SFEN();

  for (int i = 0; i < NIT; ++i) {
    const int kt1 = 2 * i + 1, kt2 = 2 * i + 2, kt3 = 2 * i + 3;
    const bool more = (i < NIT - 1);
    ldA(0, 0); ldB(b0, 0, 0); stage(0, 1, 1, kt1);
    BARX(); LG0(); SFEN(); mm(b0, acc[0][0]); BARX();
    ldB(b1, 0, 1); stage(1, 1, 1, kt1);
    BARX(); LG0(); SFEN(); mm(b1, acc[0][1]); BARX();
    ldA(0, 1); if (more) stage(0, 0, 0, kt2);
    BARX(); LG0(); SFEN(); mm(b0, acc[1][0]); BARX();
    if (more) { stage(1, 0, 0, kt2); VM4(); } else { VM0(); }
    BARX(); SFEN(); mm(b1, acc[1][1]); BARX();
    ldA(1, 0); ldB(b0, 1, 0); if (more) stage(0, 0, 1, kt2);
    BARX(); LG0(); SFEN(); mm(b0, acc[0][0]); BARX();
    ldB(b1, 1, 1); if (more) stage(1, 0, 1, kt2);
    BARX(); LG0(); SFEN(); mm(b1, acc[0][1]); BARX();
    ldA(1, 1); if (more) stage(0, 1, 0, kt3);
    BARX(); LG0(); SFEN(); mm(b0, acc[1][0]); BARX();
    if (more) { stage(1, 1, 0, kt3); VM4(); }
    BARX(); SFEN(); mm(b1, acc[1][1]);
    if (more) BARX();
  }

  // ---- epilogue: Gram partial stores ----
#pragma unroll
  for (int qm = 0; qm < 2; ++qm)
#pragma unroll
  for (int qn = 0; qn < 2; ++qn)
#pragma unroll
  for (int mi = 0; mi < 4; ++mi)
#pragma unroll
  for (int ni = 0; ni < 2; ++ni)
#pragma unroll
  for (int rr = 0; rr < 4; ++rr) {
    const int row_l = qm * 128 + wrr + mi * 16 + krow * 4 + rr;
    const int col_l = qn * 128 + wcc + ni * 16 + mrow;
    const int row = by * 256 + row_l, colg = bx * 256 + col_l;
    ((float*)o0)[(size_t)part * SPART_STRIDE + (size_t)bz * 262144 +
                 row * 512 + colg] = acc[qm][qn][mi][ni][rr];
  }
}

// -------- K6: softmax -> att_t (b,d,c); 256 blocks (32 c-rows each) --------
__global__ __launch_bounds__(256) void softmax_t(const float* __restrict__ S,
                                                 bf16* __restrict__ att_t) {
  const int b  = blockIdx.x >> 4;
  const int ct = blockIdx.x & 15;              // 16 half-tiles of 32 c
  __shared__ bf16 T[512][36];                  // [d][c_local], padded
  const int w = threadIdx.x >> 6, lane = threadIdx.x & 63;
  for (int it = 0; it < 8; ++it) {
    const int cl  = w * 8 + it;                // local c 0..31
    const int row = b * 512 + ct * 32 + cl;
    const float* p = S + (size_t)row * 512;
    float v[8];
    float mx = -1e30f;
#pragma unroll
    for (int i = 0; i < 8; ++i) { v[i] = p[lane + i * 64]; mx = fmaxf(mx, v[i]); }
    for (int off = 32; off; off >>= 1) mx = fmaxf(mx, __shfl_xor(mx, off));
    float s = 0.f;
#pragma unroll
    for (int i = 0; i < 8; ++i) { v[i] = __expf(v[i] - mx); s += v[i]; }
    for (int off = 32; off; off >>= 1) s += __shfl_xor(s, off);
    float inv = 1.f / s;
#pragma unroll
    for (int i = 0; i < 8; ++i) T[lane + i * 64][cl] = __float2bfloat16(v[i] * inv);
  }
  __syncthreads();
  bf16* outp = att_t + (size_t)b * 262144 + ct * 32;
  const int dof = threadIdx.x >> 3;            // 0..31
  const int c4  = (threadIdx.x & 7) * 4;       // 0..28
  for (int it = 0; it < 16; ++it) {
    const int d = it * 32 + dof;
    *(short4v*)(outp + (size_t)d * 512 + c4) = *(const short4v*)(&T[d][c4]);
  }
}

extern "C" void kernel_launch(void* const* d_in, const int* in_sizes, int n_in,
                              void* d_out, int out_size, void* d_ws, size_t ws_size,
                              hipStream_t stream) {
  const float* x      = (const float*)d_in[0];
  const float* norm_w = (const float*)d_in[1];
  const float* norm_b = (const float*)d_in[2];
  const float* qkv_w  = (const float*)d_in[3];
  const float* qkv_b  = (const float*)d_in[4];
  const float* proj_w = (const float*)d_in[5];
  const float* proj_b = (const float*)d_in[6];
  float* out = (float*)d_out;
  char* ws = (char*)d_ws;

  bf16*  wq    = (bf16*)(ws + OFF_WQ);
  bf16*  wp    = (bf16*)(ws + OFF_WP);
  bf16*  wvt   = (bf16*)(ws + OFF_WVT);
  float* partb = (float*)(ws + OFF_PART);
  float* ssum  = (float*)(ws + OFF_SUM);
  float* chs   = (float*)(ws + OFF_CHS);
  float* u     = (float*)(ws + OFF_U);
  float* wv_   = (float*)(ws + OFF_W);
  float* bias2 = (float*)(ws + OFF_BV2);
  bf16*  xncn  = (bf16*)(ws + OFF_XNC);
  bf16*  g2    = (bf16*)(ws + OFF_G2);     // aliases xncn (dead after Gram)
  bf16*  P     = (bf16*)(ws + OFF_P);
  bf16*  att_t = (bf16*)(ws + OFF_ATT);
  float* gpart = (float*)(ws + OFF_GP);    // 4 Gram partials, 64MB
  bf16*  w2    = (bf16*)(ws + OFF_W2);     // aliases gpart (dead after greduce)
  bf16*  w3    = (bf16*)(ws + OFF_W3);
  bf16*  xnt   = (bf16*)(ws + OFF_VT);
  float* S     = (float*)d_out;

  prep<<<5120, 256, 0, stream>>>(qkv_w, proj_w, x, wq, wp, wvt, partb, chs);
  gn_apply_t<<<dim3(64, 8, 16), 256, 0, stream>>>(x, partb, norm_w, norm_b,
                                                  xnt, xncn);
  // Gram (symmetric): tiles {(0,0),(1,1),(0,1)} x 4 parts x 16 b -> 192 blk
  gemm8p<1><<<192, 512, 0, stream>>>(xncn, xncn, 4096, 4096, 2097152LL,
                                     2097152LL, nullptr, gpart, nullptr,
                                     nullptr, nullptr);
  greduce<<<1024, 256, 0, stream>>>(gpart, g2);
  mk_ssum<<<16, 512, 0, stream>>>(chs, partb, norm_w, norm_b, ssum);
  gemv_uw<<<32, 512, 0, stream>>>(qkv_w, ssum, u, wv_);
  // P_b = Wq*[Ghi|Glo]^T: K=1024, A wraps; 128^2 tiles -> 256 blocks
  gemm128<4><<<256, 256, 0, stream>>>(wq, g2, 1024, 512, 1024, 0, 524288LL,
                                      nullptr, P, nullptr, nullptr, nullptr);
  // S_b = (P*Wk^T + corrections) * kScale; 128^2 tiles -> 256 blocks
  gemm128<5><<<256, 256, 0, stream>>>(P, wq + 512 * 512, 512, 512, 512,
                                      262144LL, 0, qkv_b, S, u, wv_, nullptr);
  softmax_t<<<256, 256, 0, stream>>>(S, att_t);
  // W2 = wp * att^T; 128^2 tiles -> 256 blocks
  gemm128<2><<<256, 256, 0, stream>>>(wp, att_t, 512, 512, 512, 0, 262144LL,
                                      nullptr, w2, nullptr, nullptr, nullptr);
  // W3 = W2 * Wv; 128^2 tiles -> 256 blocks
  gemm128<2><<<256, 256, 0, stream>>>(w2, wvt, 512, 512, 512, 262144LL, 0,
                                      nullptr, w3, nullptr, nullptr, nullptr);
  gemv_bv2<<<16, 512, 0, stream>>>(w2, qkv_b, proj_b, bias2);
  // final: out = W3*xnt^T + bias2 + resid; 2048 blocks, 8/CU
  gemm128<3><<<2048, 256, 0, stream>>>(w3, xnt, 512, 512, 512, 262144LL,
                                       2097152LL, bias2, out, nullptr, nullptr,
                                       x);
}

// Round 24
// 357.966 us; speedup vs baseline: 1.0608x; 1.0608x over previous
//
#include <hip/hip_runtime.h>
#include <hip/hip_bf16.h>

using bf16 = __hip_bfloat16;
typedef __attribute__((ext_vector_type(8))) short short8;   // 8 x bf16 (4 VGPRs)
typedef __attribute__((ext_vector_type(4))) float f32x4;
typedef __attribute__((ext_vector_type(4))) short short4v;

#define B_   16
#define C_   512
#define N_   4096
#define NG   8
#define GRP_ELEMS (64 * 4096)
static constexpr float kScale = 0.04419417382415922f;  // 512^-0.5
#define SPART_STRIDE 4194304ULL  // 16*512*512 f32 elements per Gram partial

// ---------------- memory layout ----------------
// d_ws: WQ 1.5MB | WP 0.5MB | PART/SUM/CHS/u/w | WVT | BIAS2 | Qslot | Kslot | XNT
//  Qslot: xn_cn (b,c,n) bf16 64MB -> dead after Gram -> G2 (hi|lo) 16MB @+0,
//         P bf16 16MB @+16MB, att_t 8MB @+32MB.
//  Kslot: Gram partials f32 4x16MB (dead after greduce) -> W2 8MB @+0, W3 @+8MB.
// d_out: S f32 16MB scratch; final GEMM rewrites all of d_out.
#define OFF_WQ    0ULL
#define OFF_WP    0x180000ULL
#define OFF_PART  0x204000ULL
#define OFF_SUM   0x210000ULL
#define OFF_CHS   0x218000ULL
#define OFF_U     0x220000ULL
#define OFF_W     0x230000ULL
#define OFF_WVT   0x240000ULL
#define OFF_BV2   0x2C0000ULL
#define OFF_Q     0x400000ULL
#define OFF_K     (OFF_Q  + 0x4000000ULL)
#define OFF_VT    (OFF_K  + 0x4000000ULL)   // hosts xnt (b,n,c)
#define OFF_XNC   OFF_Q
#define OFF_G2    OFF_Q
#define OFF_P     (OFF_Q + 0x1000000ULL)
#define OFF_ATT   (OFF_Q + 0x2000000ULL)
#define OFF_GP    OFF_K
#define OFF_W2    OFF_K
#define OFF_W3    (OFF_K + 0x800000ULL)

typedef __attribute__((address_space(1))) const void* as1cvp;
typedef __attribute__((address_space(3))) void* as3vp;

__device__ inline void gload_lds16(const void* g, void* l) {
  __builtin_amdgcn_global_load_lds((as1cvp)g, (as3vp)l, 16, 0, 0);
}

__device__ inline short bf16bits(float v) {
  bf16 h = __float2bfloat16(v);
  return *reinterpret_cast<short*>(&h);
}

#define BARX() __builtin_amdgcn_s_barrier()
#define SFEN() __builtin_amdgcn_sched_barrier(0)
#define LG0()  asm volatile("s_waitcnt lgkmcnt(0)" ::: "memory")
#define VM4()  asm volatile("s_waitcnt vmcnt(4)" ::: "memory")
#define VM0()  asm volatile("s_waitcnt vmcnt(0)" ::: "memory")

// -------- K0: prep = weight cvt (blocks 0..3071) + GN stats + chan sums ----
__global__ __launch_bounds__(256) void prep(const float* __restrict__ wq,
                                            const float* __restrict__ wp,
                                            const float* __restrict__ x,
                                            bf16* __restrict__ oq,
                                            bf16* __restrict__ op,
                                            bf16* __restrict__ wvt,
                                            float* __restrict__ part,
                                            float* __restrict__ chansum) {
  if (blockIdx.x < 3072) {
    int i = blockIdx.x * 256 + threadIdx.x;
    oq[i] = __float2bfloat16(wq[i]);
    if (i < 512 * 512) {
      op[i] = __float2bfloat16(wp[i]);
      const int d = i >> 9, c = i & 511;   // Wv row d, col c
      wvt[c * 512 + d] = __float2bfloat16(wq[(1024 + d) * 512 + c]);
    }
    return;
  }
  const int bid = blockIdx.x - 3072;       // 0..2047
  const int bg  = bid >> 4;                // group (b*8+g)
  const int seg = bid & 15;                // 4-channel segment
  const float4* p = (const float4*)(x + (size_t)bg * GRP_ELEMS + seg * 16384);
  float a[4] = {0.f, 0.f, 0.f, 0.f};       // per-channel sums
  float q = 0.f;
#pragma unroll
  for (int i = 0; i < 16; ++i) {           // channel j = i>>2 (t<256 exact)
    float4 v = p[threadIdx.x + i * 256];
    a[i >> 2] += v.x + v.y + v.z + v.w;
    q += v.x * v.x + v.y * v.y + v.z * v.z + v.w * v.w;
  }
  for (int off = 32; off; off >>= 1) {
#pragma unroll
    for (int j = 0; j < 4; ++j) a[j] += __shfl_xor(a[j], off);
    q += __shfl_xor(q, off);
  }
  __shared__ float red[4][5];
  int w = threadIdx.x >> 6;
  if ((threadIdx.x & 63) == 0) {
#pragma unroll
    for (int j = 0; j < 4; ++j) red[w][j] = a[j];
    red[w][4] = q;
  }
  __syncthreads();
  if (threadIdx.x == 0) {
    float c0 = red[0][0] + red[1][0] + red[2][0] + red[3][0];
    float c1 = red[0][1] + red[1][1] + red[2][1] + red[3][1];
    float c2 = red[0][2] + red[1][2] + red[2][2] + red[3][2];
    float c3 = red[0][3] + red[1][3] + red[2][3] + red[3][3];
    float Q  = red[0][4] + red[1][4] + red[2][4] + red[3][4];
    part[bid * 2]     = c0 + c1 + c2 + c3;
    part[bid * 2 + 1] = Q;
    const int b = bg >> 3, c = (bg & 7) * 64 + seg * 4;
    float* cs = chansum + b * 512 + c;
    cs[0] = c0; cs[1] = c1; cs[2] = c2; cs[3] = c3;
  }
}

// ------- K2: stats-from-partials + normalize+affine -> xnt & xncn ----------
__global__ __launch_bounds__(256) void gn_apply_t(const float* __restrict__ x,
                                                  const float* __restrict__ part,
                                                  const float* __restrict__ nw,
                                                  const float* __restrict__ nb,
                                                  bf16* __restrict__ xnt,
                                                  bf16* __restrict__ xncn) {
  const int nt = blockIdx.x;
  const int ct = blockIdx.y;
  const int b  = blockIdx.z;
  __shared__ float tile[64][65];
  const int bg = b * NG + ct;
  float Sm = 0.f, Qm = 0.f;
#pragma unroll
  for (int i = 0; i < 16; ++i) {
    Sm += part[(bg * 16 + i) * 2];
    Qm += part[(bg * 16 + i) * 2 + 1];
  }
  const float mean = Sm * (1.f / GRP_ELEMS);
  const float var  = Qm * (1.f / GRP_ELEMS) - mean * mean;
  const float rstd = rsqrtf(var + 1e-5f);

  const int r16 = threadIdx.x >> 4;        // 0..15
  const int q4  = (threadIdx.x & 15) * 4;  // 0..60
#pragma unroll
  for (int p = 0; p < 4; ++p) {
    const int cl = p * 16 + r16;
    const int c  = ct * 64 + cl;
    const float g  = nw[c] * rstd;
    const float sh = nb[c] - mean * g;
    float4 v = *(const float4*)(x + ((size_t)b * C_ + c) * N_ + nt * 64 + q4);
    const float x0 = v.x * g + sh, x1 = v.y * g + sh;
    const float x2 = v.z * g + sh, x3 = v.w * g + sh;
    tile[cl][q4] = x0; tile[cl][q4 + 1] = x1;
    tile[cl][q4 + 2] = x2; tile[cl][q4 + 3] = x3;
    short4v s4 = {bf16bits(x0), bf16bits(x1), bf16bits(x2), bf16bits(x3)};
    *(short4v*)(xncn + ((size_t)b * C_ + c) * N_ + nt * 64 + q4) = s4;
  }
  __syncthreads();
#pragma unroll
  for (int p = 0; p < 4; ++p) {
    const int nl = p * 16 + r16;
    short4v s4 = {bf16bits(tile[q4][nl]), bf16bits(tile[q4 + 1][nl]),
                  bf16bits(tile[q4 + 2][nl]), bf16bits(tile[q4 + 3][nl])};
    *(short4v*)(xnt + ((size_t)b * N_ + nt * 64 + nl) * C_ + ct * 64 + q4) = s4;
  }
}

// ---- K3: ssum[b,c] = sum_n xn = g*rowsum_x + 4096*sh (exact, from chansum) -
__global__ __launch_bounds__(512) void mk_ssum(const float* __restrict__ chansum,
                                               const float* __restrict__ part,
                                               const float* __restrict__ nw,
                                               const float* __restrict__ nb,
                                               float* __restrict__ ssum) {
  const int b = blockIdx.x, c = threadIdx.x;
  const int bg = b * NG + (c >> 6);
  float Sm = 0.f, Qm = 0.f;
#pragma unroll
  for (int i = 0; i < 16; ++i) {
    Sm += part[(bg * 16 + i) * 2];
    Qm += part[(bg * 16 + i) * 2 + 1];
  }
  const float mean = Sm * (1.f / GRP_ELEMS);
  const float var  = Qm * (1.f / GRP_ELEMS) - mean * mean;
  const float rstd = rsqrtf(var + 1e-5f);
  const float g  = nw[c] * rstd;
  const float sh = nb[c] - mean * g;
  ssum[b * 512 + c] = g * chansum[b * 512 + c] + 4096.f * sh;
}

// ---- K4: reduce Gram partials -> G2 (b,e,[hi|lo]); mirror lower-left ------
__global__ __launch_bounds__(256) void greduce(const float* __restrict__ gp,
                                               bf16* __restrict__ g2) {
  const int b  = blockIdx.x >> 6;
  const int t  = blockIdx.x & 63;
  const int te = t >> 3, tk = t & 7;
  const bool mir = (te >= 4 && tk < 4);    // lower-left quadrant: mirror
  const size_t gbase = (size_t)b * 262144;
  const int r  = threadIdx.x >> 2;         // 0..63
  const int c0 = (threadIdx.x & 3) * 16;   // 0,16,32,48
  __shared__ float T[64][65];
  const int sre = mir ? tk : te, srk = mir ? te : tk;
  const float* src = gp + gbase + (size_t)(sre * 64 + r) * 512 + srk * 64 + c0;
#pragma unroll
  for (int j = 0; j < 16; j += 4) {
    float4 v0 = *(const float4*)(src + j);
    float4 v1 = *(const float4*)(src + SPART_STRIDE + j);
    float4 v2 = *(const float4*)(src + 2 * SPART_STRIDE + j);
    float4 v3 = *(const float4*)(src + 3 * SPART_STRIDE + j);
    T[r][c0 + j]     = v0.x + v1.x + v2.x + v3.x;
    T[r][c0 + j + 1] = v0.y + v1.y + v2.y + v3.y;
    T[r][c0 + j + 2] = v0.z + v1.z + v2.z + v3.z;
    T[r][c0 + j + 3] = v0.w + v1.w + v2.w + v3.w;
  }
  __syncthreads();
  const int e = te * 64 + r;
  bf16* hi = g2 + ((size_t)b * 512 + e) * 1024 + tk * 64 + c0;
#pragma unroll
  for (int j = 0; j < 16; ++j) {
    const float g = mir ? T[c0 + j][r] : T[r][c0 + j];
    bf16 h = __float2bfloat16(g);
    hi[j]       = h;
    hi[512 + j] = __float2bfloat16(g - __bfloat162float(h));
  }
}

// ---------------- K5: u = Wq s, w = Wk s (fp32, exact) ----------------
__global__ __launch_bounds__(512) void gemv_uw(const float* __restrict__ qw,
                                               const float* __restrict__ s,
                                               float* __restrict__ u,
                                               float* __restrict__ w) {
  const int b = blockIdx.x >> 1, which = blockIdx.x & 1;
  const int c = threadIdx.x;
  const float* row = qw + (size_t)(which * 512 + c) * 512;
  const float* sv = s + b * 512;
  float acc = 0.f;
  for (int d = 0; d < 512; d += 4) {
    float4 wv = *(const float4*)(row + d);
    float4 s4 = *(const float4*)(sv + d);
    acc += wv.x * s4.x + wv.y * s4.y + wv.z * s4.z + wv.w * s4.w;
  }
  (which ? w : u)[b * 512 + c] = acc;
}

// ------- K7: bias2[b][o] = proj_b[o] + sum_d W2[b][o][d] * bv[d] -----------
__global__ __launch_bounds__(512) void gemv_bv2(const bf16* __restrict__ w2,
                                                const float* __restrict__ qkv_b,
                                                const float* __restrict__ proj_b,
                                                float* __restrict__ bias2) {
  const int b = blockIdx.x, o = threadIdx.x;
  const bf16* row = w2 + (size_t)b * 262144 + o * 512;
  float acc = proj_b[o];
  for (int d = 0; d < 512; d += 8) {
    short8 v8 = *(const short8*)(row + d);
#pragma unroll
    for (int i = 0; i < 8; ++i) {
      short t = v8[i];
      acc += __bfloat162float(*reinterpret_cast<const bf16*>(&t)) *
             qkv_b[1024 + d + i];
    }
  }
  bias2[b * 512 + o] = acc;
}

// =================================================================
// gemm128: 128x128-tile NT bf16 GEMM, BK=32 (round-4 verified core).
// 256 blocks (4x4x16), 1 block/CU — latency-optimized for the small
// per-batch 512^3 GEMMs.  4 waves (2x2), 4x4 frags of 16x16x32 MFMA.
// MODE 2: C[b] = A(/b)*B(/b)^T bf16 (P / W2 / W3 via pointer args)
// MODE 4: same, but A k-index wraps mod 512 (A=Wq, B=[Ghi|Glo], K=1024)
// MODE 5: S[b] = (A*B^T + rank-1 corr) * kScale, f32
// =================================================================
template<int MODE>
__global__ __launch_bounds__(256) void gemm128(
    const bf16* __restrict__ Ag, const bf16* __restrict__ Bg,
    int K, int lda, int ldb, long long sA, long long sB,
    const float* __restrict__ bias,
    void* __restrict__ o0, void* __restrict__ o1, void* __restrict__ o2) {
  __shared__ __align__(16) bf16 As[128 * 32];
  __shared__ __align__(16) bf16 Bs[128 * 32];
  const int s = ((blockIdx.x & 7) * 32) + (blockIdx.x >> 3);  // XCD swizzle
  const int bx = s & 3, by = (s >> 2) & 3, bz = s >> 4;
  const bf16* A = Ag + (size_t)bz * sA + (size_t)by * 128 * lda;
  const bf16* B = Bg + (size_t)bz * sB + (size_t)bx * 128 * ldb;
  const int tid  = threadIdx.x;
  const int lane = tid & 63;
  const int wv   = tid >> 6;
  const int wr = wv >> 1, wc = wv & 1;
  const int r0 = wr * 64, c0 = wc * 64;
  const int mrow = lane & 15, krow = lane >> 4;
  const int i0 = tid, i1 = tid + 256;

  f32x4 acc[4][4];
#pragma unroll
  for (int mi = 0; mi < 4; ++mi)
#pragma unroll
    for (int ni = 0; ni < 4; ++ni)
#pragma unroll
      for (int r = 0; r < 4; ++r) acc[mi][ni][r] = 0.f;

  for (int k0 = 0; k0 < K; k0 += 32) {
    const int ka = (MODE == 4) ? (k0 & 511) : k0;
    gload_lds16(A + (size_t)(i0 >> 2) * lda + ka + (i0 & 3) * 8, (char*)As + i0 * 16);
    gload_lds16(A + (size_t)(i1 >> 2) * lda + ka + (i1 & 3) * 8, (char*)As + i1 * 16);
    gload_lds16(B + (size_t)(i0 >> 2) * ldb + k0 + (i0 & 3) * 8, (char*)Bs + i0 * 16);
    gload_lds16(B + (size_t)(i1 >> 2) * ldb + k0 + (i1 & 3) * 8, (char*)Bs + i1 * 16);
    __syncthreads();
    short8 af[4], bf_[4];
#pragma unroll
    for (int mi = 0; mi < 4; ++mi)
      af[mi] = *(const short8*)((const char*)As + (r0 + mi * 16 + mrow) * 64 + krow * 16);
#pragma unroll
    for (int ni = 0; ni < 4; ++ni)
      bf_[ni] = *(const short8*)((const char*)Bs + (c0 + ni * 16 + mrow) * 64 + krow * 16);
#pragma unroll
    for (int mi = 0; mi < 4; ++mi)
#pragma unroll
      for (int ni = 0; ni < 4; ++ni)
        acc[mi][ni] = __builtin_amdgcn_mfma_f32_16x16x32_bf16(af[mi], bf_[ni],
                                                              acc[mi][ni], 0, 0, 0);
    __syncthreads();
  }

#pragma unroll
  for (int mi = 0; mi < 4; ++mi)
#pragma unroll
    for (int ni = 0; ni < 4; ++ni) {
      const int col = bx * 128 + c0 + ni * 16 + mrow;
#pragma unroll
      for (int r = 0; r < 4; ++r) {
        const int row = by * 128 + r0 + mi * 16 + krow * 4 + r;
        const float v = acc[mi][ni][r];
        if constexpr (MODE == 5) {
          const float* uu = (const float*)o1;
          const float* ww = (const float*)o2;
          const float bq = bias[row], bk = bias[512 + col];
          const float corr = uu[bz * 512 + row] * bk + bq * ww[bz * 512 + col] +
                             4096.f * bq * bk;
          ((float*)o0)[(size_t)bz * 262144 + row * 512 + col] = (v + corr) * kScale;
        } else {
          ((bf16*)o0)[(size_t)bz * 262144 + row * 512 + col] = __float2bfloat16(v);
        }
      }
    }
}

// =================================================================
// 8-phase 256x256 NT bf16 GEMM (round-8/10 verified schedule, UNCHANGED).
// MODE 1: Gram 192 blk, K=1024 split-4 over n: tiles {(0,0),(1,1),(0,1)}
// MODE 3: final 512 blk, K=512: out = W3*xnt^T + bias2[b] + resid (f32)
// =================================================================
template<int MODE>
__global__ __launch_bounds__(512, 2) void gemm8p(
    const bf16* __restrict__ Ag, const bf16* __restrict__ Bg,
    int lda, int ldb, long long sA, long long sB,
    const float* __restrict__ bias,
    void* __restrict__ o0, void* __restrict__ o1, void* __restrict__ o2,
    const float* __restrict__ resid) {
  __shared__ __align__(16) bf16 smem[8][8192];  // [A:0-3 | B:4-7][buf*2+half]

  constexpr int NIT = (MODE == 1) ? 8 : 4;
  const int id = blockIdx.x;
  int bx, by, bz, part;
  if constexpr (MODE == 1) {
    const int s = (id & 7) * 24 + (id >> 3);    // 192 blocks
    const int tile = s % 3, rest = s / 3;       // tile: 0=(0,0) 1=(1,1) 2=(0,1)
    part = rest & 3; bz = rest >> 2;
    by = (tile == 1) ? 1 : 0;
    bx = (tile == 0) ? 0 : 1;
  } else {
    const int s = (id & 7) * 64 + (id >> 3);    // 512 blocks
    by = s & 1;  bx = (s >> 1) & 15;  bz = s >> 5; part = 0;
  }

  const bf16* Apan = Ag + (size_t)bz * sA + (size_t)by * 256 * lda + (size_t)part * 1024;
  const bf16* Bpan = Bg + (size_t)bz * sB + (size_t)bx * 256 * ldb + (size_t)part * 1024;

  const int tid  = threadIdx.x;
  const int lane = tid & 63;
  const int wid  = tid >> 6;
  const int wr   = wid >> 2;
  const int wc   = wid & 3;
  const int mrow = lane & 15, krow = lane >> 4;
  const int wrr  = wr * 64, wcc = wc * 32;

  // stage one half-tile (2 x gload_lds16/thread); inverse-swizzled source
  auto stage = [&](int mat, int buf, int half, int kt) {
    const bf16* gb = mat ? Bpan : Apan;
    const int ld = mat ? ldb : lda;
    char* reg = (char*)smem[mat * 4 + buf * 2 + half];
#pragma unroll
    for (int j = 0; j < 2; ++j) {
      const int idx = j * 512 + tid;
      const int r   = idx >> 3;
      const int c8  = (tid & 7) ^ (r & 7);
      gload_lds16(gb + (size_t)(half * 128 + r) * ld + kt * 64 + c8 * 8,
                  reg + idx * 16);
    }
  };

  short8 a[4][2], b0[2][2], b1[2][2];
  auto ldA = [&](int buf, int qm) {
    const char* reg = (const char*)smem[buf * 2 + qm];
#pragma unroll
    for (int mi = 0; mi < 4; ++mi) {
      const int lr = wrr + mi * 16 + mrow;
#pragma unroll
      for (int s2 = 0; s2 < 2; ++s2)
        a[mi][s2] = *(const short8*)(reg + lr * 128 +
                                     (((s2 * 4 + krow) ^ (lr & 7)) << 4));
    }
  };
  auto ldB = [&](short8 (&b)[2][2], int buf, int qn) {
    const char* reg = (const char*)smem[4 + buf * 2 + qn];
#pragma unroll
    for (int ni = 0; ni < 2; ++ni) {
      const int lr = wcc + ni * 16 + mrow;
#pragma unroll
      for (int s2 = 0; s2 < 2; ++s2)
        b[ni][s2] = *(const short8*)(reg + lr * 128 +
                                     (((s2 * 4 + krow) ^ (lr & 7)) << 4));
    }
  };

  f32x4 acc[2][2][4][2];
#pragma unroll
  for (int p = 0; p < 2; ++p)
#pragma unroll
    for (int q = 0; q < 2; ++q)
#pragma unroll
      for (int m = 0; m < 4; ++m)
#pragma unroll
        for (int n = 0; n < 2; ++n)
#pragma unroll
          for (int r = 0; r < 4; ++r) acc[p][q][m][n][r] = 0.f;

  auto mm = [&](short8 (&b)[2][2], f32x4 (&c)[4][2]) {
    __builtin_amdgcn_s_setprio(1);
#pragma unroll
    for (int mi = 0; mi < 4; ++mi)
#pragma unroll
      for (int ni = 0; ni < 2; ++ni)
#pragma unroll
        for (int s2 = 0; s2 < 2; ++s2)
          c[mi][ni] = __builtin_amdgcn_mfma_f32_16x16x32_bf16(
              a[mi][s2], b[ni][s2], c[mi][ni], 0, 0, 0);
    __builtin_amdgcn_s_setprio(0);
  };

  // ---- prologue: K-tile0 all 4 halves, K-tile1 Aa+Ba ----
  stage(0, 0, 0, 0); stage(0, 0, 1, 0); stage(1, 0, 0, 0); stage(1, 0, 1, 0);
  stage(0, 1, 0, 1); stage(1, 1, 0, 1);
  VM4(); BARX(); SFEN();

  // ---- main loop: iter i computes K-tiles 2i (buf0), 2i+1 (buf1) ----
  for (int i = 0; i < NIT; ++i) {
    const int kt1 = 2 * i + 1, kt2 = 2 * i + 2, kt3 = 2 * i + 3;
    const bool more = (i < NIT - 1);
    ldA(0, 0); ldB(b0, 0, 0); stage(0, 1, 1, kt1);
    BARX(); LG0(); SFEN(); mm(b0, acc[0][0]); BARX();
    ldB(b1, 0, 1); stage(1, 1, 1, kt1);
    BARX(); LG0(); SFEN(); mm(b1, acc[0][1]); BARX();
    ldA(0, 1); if (more) stage(0, 0, 0, kt2);
    BARX(); LG0(); SFEN(); mm(b0, acc[1][0]); BARX();
    if (more) { stage(1, 0, 0, kt2); VM4(); } else { VM0(); }
    BARX(); SFEN(); mm(b1, acc[1][1]); BARX();
    ldA(1, 0); ldB(b0, 1, 0); if (more) stage(0, 0, 1, kt2);
    BARX(); LG0(); SFEN(); mm(b0, acc[0][0]); BARX();
    ldB(b1, 1, 1); if (more) stage(1, 0, 1, kt2);
    BARX(); LG0(); SFEN(); mm(b1, acc[0][1]); BARX();
    ldA(1, 1); if (more) stage(0, 1, 0, kt3);
    BARX(); LG0(); SFEN(); mm(b0, acc[1][0]); BARX();
    if (more) { stage(1, 1, 0, kt3); VM4(); }
    BARX(); SFEN(); mm(b1, acc[1][1]);
    if (more) BARX();
  }

  // ---- epilogue ----
#pragma unroll
  for (int qm = 0; qm < 2; ++qm)
#pragma unroll
  for (int qn = 0; qn < 2; ++qn)
#pragma unroll
  for (int mi = 0; mi < 4; ++mi)
#pragma unroll
  for (int ni = 0; ni < 2; ++ni)
#pragma unroll
  for (int rr = 0; rr < 4; ++rr) {
    const int row_l = qm * 128 + wrr + mi * 16 + krow * 4 + rr;
    const int col_l = qn * 128 + wcc + ni * 16 + mrow;
    float v = acc[qm][qn][mi][ni][rr];
    if constexpr (MODE == 1) {
      const int row = by * 256 + row_l, colg = bx * 256 + col_l;
      ((float*)o0)[(size_t)part * SPART_STRIDE + (size_t)bz * 262144 +
                   row * 512 + colg] = v;        // raw Gram partial
    } else {
      const int o = by * 256 + row_l;
      const int n = bx * 256 + col_l;
      const size_t addr = ((size_t)bz * C_ + o) * N_ + n;
      ((float*)o0)[addr] = v + bias[(bz << 9) + o] + resid[addr];
    }
  }
}

// -------- K6: softmax -> att_t (b,d,c); 256 blocks (32 c-rows each) --------
__global__ __launch_bounds__(256) void softmax_t(const float* __restrict__ S,
                                                 bf16* __restrict__ att_t) {
  const int b  = blockIdx.x >> 4;
  const int ct = blockIdx.x & 15;              // 16 half-tiles of 32 c
  __shared__ bf16 T[512][36];                  // [d][c_local], padded
  const int w = threadIdx.x >> 6, lane = threadIdx.x & 63;
  for (int it = 0; it < 8; ++it) {
    const int cl  = w * 8 + it;                // local c 0..31
    const int row = b * 512 + ct * 32 + cl;
    const float* p = S + (size_t)row * 512;
    float v[8];
    float mx = -1e30f;
#pragma unroll
    for (int i = 0; i < 8; ++i) { v[i] = p[lane + i * 64]; mx = fmaxf(mx, v[i]); }
    for (int off = 32; off; off >>= 1) mx = fmaxf(mx, __shfl_xor(mx, off));
    float s = 0.f;
#pragma unroll
    for (int i = 0; i < 8; ++i) { v[i] = __expf(v[i] - mx); s += v[i]; }
    for (int off = 32; off; off >>= 1) s += __shfl_xor(s, off);
    float inv = 1.f / s;
#pragma unroll
    for (int i = 0; i < 8; ++i) T[lane + i * 64][cl] = __float2bfloat16(v[i] * inv);
  }
  __syncthreads();
  bf16* outp = att_t + (size_t)b * 262144 + ct * 32;
  const int dof = threadIdx.x >> 3;            // 0..31
  const int c4  = (threadIdx.x & 7) * 4;       // 0..28
  for (int it = 0; it < 16; ++it) {
    const int d = it * 32 + dof;
    *(short4v*)(outp + (size_t)d * 512 + c4) = *(const short4v*)(&T[d][c4]);
  }
}

extern "C" void kernel_launch(void* const* d_in, const int* in_sizes, int n_in,
                              void* d_out, int out_size, void* d_ws, size_t ws_size,
                              hipStream_t stream) {
  const float* x      = (const float*)d_in[0];
  const float* norm_w = (const float*)d_in[1];
  const float* norm_b = (const float*)d_in[2];
  const float* qkv_w  = (const float*)d_in[3];
  const float* qkv_b  = (const float*)d_in[4];
  const float* proj_w = (const float*)d_in[5];
  const float* proj_b = (const float*)d_in[6];
  float* out = (float*)d_out;
  char* ws = (char*)d_ws;

  bf16*  wq    = (bf16*)(ws + OFF_WQ);
  bf16*  wp    = (bf16*)(ws + OFF_WP);
  bf16*  wvt   = (bf16*)(ws + OFF_WVT);
  float* partb = (float*)(ws + OFF_PART);
  float* ssum  = (float*)(ws + OFF_SUM);
  float* chs   = (float*)(ws + OFF_CHS);
  float* u     = (float*)(ws + OFF_U);
  float* wv_   = (float*)(ws + OFF_W);
  float* bias2 = (float*)(ws + OFF_BV2);
  bf16*  xncn  = (bf16*)(ws + OFF_XNC);
  bf16*  g2    = (bf16*)(ws + OFF_G2);     // aliases xncn (dead after Gram)
  bf16*  P     = (bf16*)(ws + OFF_P);
  bf16*  att_t = (bf16*)(ws + OFF_ATT);
  float* gpart = (float*)(ws + OFF_GP);    // 4 Gram partials, 64MB
  bf16*  w2    = (bf16*)(ws + OFF_W2);     // aliases gpart (dead after greduce)
  bf16*  w3    = (bf16*)(ws + OFF_W3);
  bf16*  xnt   = (bf16*)(ws + OFF_VT);
  float* S     = (float*)d_out;

  prep<<<5120, 256, 0, stream>>>(qkv_w, proj_w, x, wq, wp, wvt, partb, chs);
  gn_apply_t<<<dim3(64, 8, 16), 256, 0, stream>>>(x, partb, norm_w, norm_b,
                                                  xnt, xncn);
  // Gram (symmetric): tiles {(0,0),(1,1),(0,1)} x 4 parts x 16 b -> 192 blk
  gemm8p<1><<<192, 512, 0, stream>>>(xncn, xncn, 4096, 4096, 2097152LL,
                                     2097152LL, nullptr, gpart, nullptr,
                                     nullptr, nullptr);
  greduce<<<1024, 256, 0, stream>>>(gpart, g2);
  mk_ssum<<<16, 512, 0, stream>>>(chs, partb, norm_w, norm_b, ssum);
  gemv_uw<<<32, 512, 0, stream>>>(qkv_w, ssum, u, wv_);
  // P_b = Wq*[Ghi|Glo]^T: K=1024, A wraps; 128^2 tiles -> 256 blocks
  gemm128<4><<<256, 256, 0, stream>>>(wq, g2, 1024, 512, 1024, 0, 524288LL,
                                      nullptr, P, nullptr, nullptr);
  // S_b = (P*Wk^T + corrections) * kScale; 128^2 tiles -> 256 blocks
  gemm128<5><<<256, 256, 0, stream>>>(P, wq + 512 * 512, 512, 512, 512,
                                      262144LL, 0, qkv_b, S, u, wv_);
  softmax_t<<<256, 256, 0, stream>>>(S, att_t);
  // W2 = wp * att^T; 128^2 tiles -> 256 blocks
  gemm128<2><<<256, 256, 0, stream>>>(wp, att_t, 512, 512, 512, 0, 262144LL,
                                      nullptr, w2, nullptr, nullptr);
  // W3 = W2 * Wv; 128^2 tiles -> 256 blocks
  gemm128<2><<<256, 256, 0, stream>>>(w2, wvt, 512, 512, 512, 262144LL, 0,
                                      nullptr, w3, nullptr, nullptr);
  gemv_bv2<<<16, 512, 0, stream>>>(w2, qkv_b, proj_b, bias2);
  // out = W3 * xn + bias2 + resid: M=512, N=65536 -> 512 blocks (8-phase)
  gemm8p<3><<<512, 512, 0, stream>>>(w3, xnt, 512, 512, 262144LL, 2097152LL,
                                     bias2, out, nullptr, nullptr, x);
}